// Round 11
// baseline (21.106 us; speedup 1.0000x reference)
//
#include <hip/hip_runtime.h>

// Problem constants (match reference setup_inputs)
#define BATCH    2
#define NPART    4096
#define NTHREADS 256
#define IBLK     4                    // i per block
#define ILANES   2                    // lane slots in i-dim (2 i packed per lane)
#define JCH      (NTHREADS / ILANES)  // 128 j-chunks per block
#define JLEN     (NPART / JCH)        // 32 j per chunk
#define NIB      (NPART / IBLK)       // 1024 i-blocks per batch
#define NWAVES   (NTHREADS / 64)      // 4 waves per block

typedef float v2f __attribute__((ext_vector_type(2)));

// One (j, 2-i) interaction. MASKED handles the i==j diagonal (r2==0 exactly).
template <bool MASKED>
__device__ inline void lj_body(float jx, float jy, float jz,
                               v2f qx, v2f qy, v2f qz,
                               v2f& fx, v2f& fy, v2f& fz) {
    const v2f dx = qx - (v2f)jx;
    const v2f dy = qy - (v2f)jy;
    const v2f dz = qz - (v2f)jz;
    v2f r2 = dx * dx;
    r2 = __builtin_elementwise_fma(dy, dy, r2);
    r2 = __builtin_elementwise_fma(dz, dz, r2);
    v2f inv;
    if (MASKED) {   // r2==0.0f exactly <=> i==j (reference's mask semantics)
        inv.x = (r2.x > 0.0f) ? __builtin_amdgcn_rcpf(r2.x) : 0.0f;
        inv.y = (r2.y > 0.0f) ? __builtin_amdgcn_rcpf(r2.y) : 0.0f;
    } else {
        inv.x = __builtin_amdgcn_rcpf(r2.x);
        inv.y = __builtin_amdgcn_rcpf(r2.y);
    }
    const v2f inv2 = inv * inv;
    const v2f s6 = inv2 * inv;                                      // sigma = 1
    const v2f c1 = __builtin_elementwise_fma((v2f)48.0f, s6, (v2f)(-24.0f));
    const v2f coeff = (inv * s6) * c1;     // 24*inv*s6*(2*s6-1)
    fx = __builtin_elementwise_fma(coeff, dx, fx);
    fy = __builtin_elementwise_fma(coeff, dy, fy);
    fz = __builtin_elementwise_fma(coeff, dz, fz);
}

// This lane's 32-j chunk: 24 float4 loads, 4 j per triple.
template <bool MASKED>
__device__ inline void chunk_loop(const float4* __restrict__ jq4,
                                  v2f qx, v2f qy, v2f qz,
                                  v2f& fx, v2f& fy, v2f& fz) {
    #pragma unroll 2
    for (int it = 0; it < JLEN / 4; ++it) {
        const float4 A = jq4[3 * it + 0];   // x0 y0 z0 x1
        const float4 B = jq4[3 * it + 1];   // y1 z1 x2 y2
        const float4 C = jq4[3 * it + 2];   // z2 x3 y3 z3
        lj_body<MASKED>(A.x, A.y, A.z, qx, qy, qz, fx, fy, fz);
        lj_body<MASKED>(A.w, B.x, B.y, qx, qy, qz, fx, fy, fz);
        lj_body<MASKED>(B.z, B.w, C.x, qx, qy, qz, fx, fy, fz);
        lj_body<MASKED>(C.y, C.z, C.w, qx, qy, qz, fx, fy, fz);
    }
}

// Fully fused single dispatch. Block owns 4 i's x all 4096 j (128 chunks of 32
// across lanes). Reduction: 5-step shfl_xor tree over the jc lane-bits, then
// 48 floats through LDS. 2048 blocks x 4 waves -> 8 blocks/CU, 8 waves/SIMD.
__global__ __launch_bounds__(NTHREADS, 8) void lj_fused(
        const float* __restrict__ q, const float* __restrict__ p,
        const float* __restrict__ m, float* __restrict__ dq,
        float* __restrict__ dp) {
    __shared__ float red2[NWAVES * 12];   // per wave: 2 il x 6 components

    const int ib = blockIdx.x;
    const int b  = blockIdx.y;
    const int t  = threadIdx.x;
    const int il = t & 1;
    const int jc = t >> 1;                // 0..127

    const float* qb = q + (size_t)b * NPART * 3;

    const int i0 = ib * IBLK + il;        // first i of this lane
    const int i1 = i0 + ILANES;           // second i of this lane
    const v2f qx = {qb[i0 * 3 + 0], qb[i1 * 3 + 0]};
    const v2f qy = {qb[i0 * 3 + 1], qb[i1 * 3 + 1]};
    const v2f qz = {qb[i0 * 3 + 2], qb[i1 * 3 + 2]};

    v2f fx = (v2f)0.0f, fy = (v2f)0.0f, fz = (v2f)0.0f;

    const float4* jq4 = (const float4*)(qb + (size_t)jc * JLEN * 3);

    // Only the wave whose j-chunks contain this block's i-range can hit i==j.
    const int diagc = ib >> 3;            // (ib*IBLK)/JLEN
    if (__any(jc == diagc)) {
        chunk_loop<true >(jq4, qx, qy, qz, fx, fy, fz);
    } else {
        chunk_loop<false>(jq4, qx, qy, qz, fx, fy, fz);
    }

    // In-wave reduce over jc (lane bits 1..5): all lanes end with their
    // il-parity's sum; lanes 0,1 publish.
    #pragma unroll
    for (int msk = 2; msk <= 32; msk <<= 1) {
        fx.x += __shfl_xor(fx.x, msk); fx.y += __shfl_xor(fx.y, msk);
        fy.x += __shfl_xor(fy.x, msk); fy.y += __shfl_xor(fy.y, msk);
        fz.x += __shfl_xor(fz.x, msk); fz.y += __shfl_xor(fz.y, msk);
    }
    const int w    = t >> 6;
    const int lane = t & 63;
    if (lane < 2) {    // lane == il here
        float* r = &red2[w * 12 + lane * 6];
        r[0] = fx.x; r[1] = fx.y;
        r[2] = fy.x; r[3] = fy.y;
        r[4] = fz.x; r[5] = fz.y;
    }
    __syncthreads();

    // 12 outputs: (c, i-in-block). Sum the 4 wave partials; fuse dq = p/m.
    if (t < 12) {
        const int c   = t >> 2;        // 0..2
        const int ii  = t & 3;         // i within block
        const int h   = ii >> 1;       // packed half
        const int il2 = ii & 1;
        const int slot = il2 * 6 + c * 2 + h;
        float s = 0.0f;
        #pragma unroll
        for (int wv = 0; wv < NWAVES; ++wv) s += red2[wv * 12 + slot];
        const size_t gi = (size_t)b * NPART + ib * IBLK + ii;
        dp[gi * 3 + c] = s;
        dq[gi * 3 + c] = p[gi * 3 + c] / m[gi];   // exact IEEE div, tiny count
    }
}

extern "C" void kernel_launch(void* const* d_in, const int* in_sizes, int n_in,
                              void* d_out, int out_size, void* d_ws, size_t ws_size,
                              hipStream_t stream) {
    const float* q = (const float*)d_in[0];
    const float* p = (const float*)d_in[1];
    const float* m = (const float*)d_in[2];
    // d_in[3] = t, unused by the reference outputs

    const int n_elem = BATCH * NPART * 3;   // 24576 per output tensor
    float* dq_out = (float*)d_out;          // first output: dq
    float* dp_out = (float*)d_out + n_elem; // second output: dp

    dim3 grid(NIB, BATCH);                  // 2048 blocks x 256 threads
    lj_fused<<<grid, NTHREADS, 0, stream>>>(q, p, m, dq_out, dp_out);
}